// Round 13
// baseline (139.856 us; speedup 1.0000x reference)
//
#include <hip/hip_runtime.h>
#include <stdint.h>

#define B_ 16
#define N_ 4096
#define R_ 256

typedef short bf16x8 __attribute__((ext_vector_type(8)));
typedef float f32x4 __attribute__((ext_vector_type(4)));
typedef uint32_t u32;

// V[b,n,i] = (n==i) ? 1 : (n>i ? param[b,n,i] : 0)
// Pipeline: S = V^T V (split-bf16 MFMA partials, packed-u32 LDS staging) ->
// reduce (tile-region only, in place) -> solve (LDS-resident triangular S,
// pipelined panel reads, DPP wave-sums, W packed hi|lo bf16) ->
// Q = E - V W (MFMA, DOUBLE-BUFFERED global_load_lds + counted vmcnt:
// T3/T4 -- DMAs stay in flight across raw s_barriers, never drained to 0
// inside the loop).
//
// Split: fp32 x ~= hi + lo, both TRUNCATED bf16; x*y ~= xh*yh+xh*yl+xl*yh.

__device__ __forceinline__ u32 pack_split(float x) {
  u32 u = __float_as_uint(x);
  u32 h = u & 0xffff0000u;
  float l = x - __uint_as_float(h);
  return h | (__float_as_uint(l) >> 16);
}

__device__ __forceinline__ void unpack8(const u32* w, bf16x8& hi, bf16x8& lo) {
  union { u32 u[4]; bf16x8 v; } H, L;
#pragma unroll
  for (int i = 0; i < 4; ++i) {
    u32 a = w[2 * i], b = w[2 * i + 1];
    H.u[i] = (a >> 16) | (b & 0xffff0000u);
    L.u[i] = (a & 0xffffu) | (b << 16);
  }
  hi = H.v; lo = L.v;
}

// Packed-u32 frag read from swizzled [row][32-word] LDS tile.
__device__ __forceinline__ void read_frag(const u32* rowbase, int row, int q2,
                                          bf16x8& hi, bf16x8& lo) {
  u32 w[8];
  const int s = row & 7;
  *(uint4*)&w[0] = *(const uint4*)(rowbase + (((q2    ) ^ s) << 2));
  *(uint4*)&w[4] = *(const uint4*)(rowbase + (((q2 + 1) ^ s) << 2));
  unpack8(w, hi, lo);
}

// Raw-fp32 frag read + on-the-fly truncating split.
__device__ __forceinline__ void read_frag_f(const float* rowbase, int row, int q2,
                                            bf16x8& hi, bf16x8& lo) {
  float w[8];
  const int s = row & 7;
  *(float4*)&w[0] = *(const float4*)(rowbase + (((q2    ) ^ s) << 2));
  *(float4*)&w[4] = *(const float4*)(rowbase + (((q2 + 1) ^ s) << 2));
  union { u32 u[4]; bf16x8 v; } H, L;
#pragma unroll
  for (int i = 0; i < 4; ++i) {
    u32 a = __float_as_uint(w[2 * i]);
    u32 b = __float_as_uint(w[2 * i + 1]);
    u32 ah = a & 0xffff0000u, bh = b & 0xffff0000u;
    float la = w[2 * i]     - __uint_as_float(ah);
    float lb = w[2 * i + 1] - __uint_as_float(bh);
    H.u[i] = (a >> 16) | bh;
    L.u[i] = (__float_as_uint(la) >> 16) | (__float_as_uint(lb) & 0xffff0000u);
  }
  hi = H.v; lo = L.v;
}

__device__ __forceinline__ f32x4 mm3(bf16x8 ah, bf16x8 al, bf16x8 bh, bf16x8 bl,
                                     f32x4 c) {
  c = __builtin_amdgcn_mfma_f32_16x16x32_bf16(al, bh, c, 0, 0, 0);
  c = __builtin_amdgcn_mfma_f32_16x16x32_bf16(ah, bl, c, 0, 0, 0);
  c = __builtin_amdgcn_mfma_f32_16x16x32_bf16(ah, bh, c, 0, 0, 0);
  return c;
}

typedef __attribute__((address_space(1))) const u32* gas_p;
typedef __attribute__((address_space(3))) u32* las_p;
__device__ __forceinline__ void async_cp16(void* lds, const void* g) {
  __builtin_amdgcn_global_load_lds((gas_p)g, (las_p)lds, 16, 0, 0);
}

// ---------------------------------------------------------------------------
// K1: partial Gram via MFMA (unchanged R12/R10 form).
// ---------------------------------------------------------------------------
__global__ __launch_bounds__(256) void gram_kernel(const float* __restrict__ param,
                                                   float* __restrict__ SP) {
  const int tile = blockIdx.x, chunk = blockIdx.y, b = blockIdx.z;
  const int j0 = (tile == 2) ? 128 : 0;
  const int k0 = (tile == 0) ? 0 : 128;
  const float* __restrict__ P = param + (size_t)b * N_ * R_;

  __shared__ u32 VT[256][32];

  const int t = threadIdx.x;
  const int lane = t & 63, wv = t >> 6;
  const int wr = wv >> 1, wc = wv & 1;
  const int l15 = lane & 15, q = lane >> 4;
  const int bbase = (tile == 1) ? 128 : 0;

  f32x4 acc[4][4];
#pragma unroll
  for (int i = 0; i < 4; ++i)
#pragma unroll
    for (int j = 0; j < 4; ++j) acc[i][j] = (f32x4){0.f, 0.f, 0.f, 0.f};

  const int nb = chunk * 256;
  const int ns = (nb > k0) ? nb : k0;
  const int ne = nb + 256;

  float ld[32];

  const int ct1 = t;
  const int ct0 = t & 127;
  const int gc0 = j0 + ct0;
  const int hb  = t >> 7;

  auto do_load = [&](int n0) {
    if (tile == 1) {
#pragma unroll
      for (int ri = 0; ri < 8; ++ri)
#pragma unroll
        for (int s = 0; s < 4; ++s)
          ld[4 * ri + s] = P[(size_t)(n0 + 4 * ri + s) * R_ + ct1];
    } else {
#pragma unroll
      for (int ri = 0; ri < 4; ++ri)
#pragma unroll
        for (int s = 0; s < 4; ++s)
          ld[4 * ri + s] = P[(size_t)(n0 + 4 * (2 * ri + hb) + s) * R_ + gc0];
    }
  };

  auto do_write = [&](int n0) {
    if (tile == 1) {
#pragma unroll
      for (int ri = 0; ri < 8; ++ri) {
        u32 qw[4];
#pragma unroll
        for (int s = 0; s < 4; ++s) {
          int n = n0 + 4 * ri + s;
          float v = (n == ct1) ? 1.f : ((n > ct1) ? ld[4 * ri + s] : 0.f);
          qw[s] = pack_split(v);
        }
        *(uint4*)&VT[ct1][((ri ^ (ct1 & 7)) << 2)] = *(uint4*)qw;
      }
    } else {
#pragma unroll
      for (int ri = 0; ri < 4; ++ri) {
        int ch = 2 * ri + hb;
        u32 qw[4];
#pragma unroll
        for (int s = 0; s < 4; ++s) {
          int n = n0 + 4 * ch + s;
          float v = (n == gc0) ? 1.f : ((n > gc0) ? ld[4 * ri + s] : 0.f);
          qw[s] = pack_split(v);
        }
        *(uint4*)&VT[ct0][((ch ^ (ct0 & 7)) << 2)] = *(uint4*)qw;
      }
    }
  };

  do_load(ns);
  for (int n0 = ns; n0 < ne; n0 += 32) {
    do_write(n0);
    __syncthreads();
    if (n0 + 32 < ne) do_load(n0 + 32);

    bf16x8 Ah[4], Al[4];
#pragma unroll
    for (int mt = 0; mt < 4; ++mt) {
      int row = 64 * wr + 16 * mt + l15;
      read_frag(&VT[row][0], row, 2 * q, Ah[mt], Al[mt]);
    }
#pragma unroll
    for (int nt = 0; nt < 4; ++nt) {
      int brow = bbase + 64 * wc + 16 * nt + l15;
      bf16x8 bh, bl;
      read_frag(&VT[brow][0], brow, 2 * q, bh, bl);
#pragma unroll
      for (int mt = 0; mt < 4; ++mt)
        acc[mt][nt] = mm3(Ah[mt], Al[mt], bh, bl, acc[mt][nt]);
    }
    __syncthreads();
  }

  float* Sp = SP + (size_t)(chunk * 16 + b) * (R_ * R_);
#pragma unroll
  for (int mt = 0; mt < 4; ++mt)
#pragma unroll
    for (int nt = 0; nt < 4; ++nt) {
      int jj = j0 + 64 * wr + 16 * mt + 4 * q;
      int kk = k0 + 64 * wc + 16 * nt + l15;
#pragma unroll
      for (int r = 0; r < 4; ++r)
        Sp[(size_t)(jj + r) * R_ + kk] = acc[mt][nt][r];
    }
}

// ---------------------------------------------------------------------------
// reduce: sum 16 chunks into chunk 0, tile region only. grid (48, 16).
// ---------------------------------------------------------------------------
__global__ __launch_bounds__(256) void reduce_kernel(float* __restrict__ SP) {
  const int b = blockIdx.y;
  int j = blockIdx.x * 256 + threadIdx.x;
  int r, c4;
  if (j < 8192) { r = j >> 6; c4 = j & 63; }
  else { int jj = j - 8192; r = 128 + (jj >> 5); c4 = 32 + (jj & 31); }
  size_t idx = (size_t)b * 16384 + (size_t)r * 64 + c4;
  float4* sp = (float4*)SP;
  float4 a = sp[idx];
#pragma unroll
  for (int c = 1; c < 16; ++c) {
    float4 v = sp[idx + (size_t)c * 262144];
    a.x += v.x; a.y += v.y; a.z += v.z; a.w += v.w;
  }
  sp[idx] = a;
}

#define DPP_ADD(v, ctrl, rmask)                                              \
  v += __int_as_float(__builtin_amdgcn_update_dpp(                           \
      0, __float_as_int(v), ctrl, rmask, 0xf, true))

// ---------------------------------------------------------------------------
// K2: wave-per-column backward substitution over LDS-resident triangular S.
// (unchanged R12)
// ---------------------------------------------------------------------------
__global__ __launch_bounds__(1024) void solve_kernel(const float* __restrict__ param,
                                                     const float* __restrict__ S,
                                                     u32* __restrict__ WtP) {
  extern __shared__ float tri[];
  const int t    = threadIdx.x;
  const int lane = t & 63;
  const int wave = t >> 6;
  const int b    = blockIdx.x >> 4;
  const int jg   = blockIdx.x & 15;
  const int k    = jg + 16 * wave;
  const float* __restrict__ Sb = S + (size_t)b * R_ * R_;
  const float* __restrict__ Pb = param + (size_t)b * N_ * R_;

  float4 x = *(const float4*)(Pb + (size_t)k * R_ + 4 * lane);
  {
    int c0 = 4 * lane;
    x.x = (c0     == k) ? 1.f : ((c0     < k) ? x.x : 0.f);
    x.y = (c0 + 1 == k) ? 1.f : ((c0 + 1 < k) ? x.y : 0.f);
    x.z = (c0 + 2 == k) ? 1.f : ((c0 + 2 < k) ? x.z : 0.f);
    x.w = (c0 + 3 == k) ? 1.f : ((c0 + 3 < k) ? x.w : 0.f);
  }

  const float4* S4 = (const float4*)Sb;
#pragma unroll
  for (int m = 0; m < 16; ++m) {
    int idx = t + 1024 * m;
    int r  = idx >> 6;
    int c4 = idx & 63;
    int g  = r >> 2;
    if (c4 >= g) {
      float4 v = S4[idx];
      int rowlen = 256 - 4 * g;
      int addr = 1024 * g - 8 * g * (g - 1) + (r & 3) * rowlen + 4 * (c4 - g);
      *(float4*)&tri[addr] = v;
    }
  }
  __syncthreads();

  float4 w = make_float4(0.f, 0.f, 0.f, 0.f);
  const int k4 = k >> 2;
  int rowlen = 256 - 4 * k4;
  int base   = 1024 * k4 - 8 * k4 * (k4 - 1);

  {
    const float* rb = tri + base + 4 * lane - 4 * k4;
    float4 rA0 = *(const float4*)(rb);
    float4 rA1 = *(const float4*)(rb + rowlen);
    float4 rA2 = *(const float4*)(rb + 2 * rowlen);
    float4 rA3 = *(const float4*)(rb + 3 * rowlen);

    for (int r4 = k4;; --r4) {
      const bool more = (r4 > 0);

      float s0 = fmaf(rA0.x, w.x, fmaf(rA0.y, w.y, fmaf(rA0.z, w.z, rA0.w * w.w)));
      float s1 = fmaf(rA1.x, w.x, fmaf(rA1.y, w.y, fmaf(rA1.z, w.z, rA1.w * w.w)));
      float s2 = fmaf(rA2.x, w.x, fmaf(rA2.y, w.y, fmaf(rA2.z, w.z, rA2.w * w.w)));
      float s3 = fmaf(rA3.x, w.x, fmaf(rA3.y, w.y, fmaf(rA3.z, w.z, rA3.w * w.w)));

      float4 rB0, rB1, rB2, rB3;
      int nrl = rowlen, nbs = base;
      if (more) {
        nrl = rowlen + 4;
        nbs = base - 4 * nrl;
        const float* rbn = tri + nbs + 4 * lane - 4 * (r4 - 1);
        rB0 = *(const float4*)(rbn);
        rB1 = *(const float4*)(rbn + nrl);
        rB2 = *(const float4*)(rbn + 2 * nrl);
        rB3 = *(const float4*)(rbn + 3 * nrl);
      }
      __builtin_amdgcn_sched_barrier(0);

      DPP_ADD(s0, 0x111, 0xf); DPP_ADD(s1, 0x111, 0xf);
      DPP_ADD(s2, 0x111, 0xf); DPP_ADD(s3, 0x111, 0xf);
      DPP_ADD(s0, 0x112, 0xf); DPP_ADD(s1, 0x112, 0xf);
      DPP_ADD(s2, 0x112, 0xf); DPP_ADD(s3, 0x112, 0xf);
      DPP_ADD(s0, 0x114, 0xf); DPP_ADD(s1, 0x114, 0xf);
      DPP_ADD(s2, 0x114, 0xf); DPP_ADD(s3, 0x114, 0xf);
      DPP_ADD(s0, 0x118, 0xf); DPP_ADD(s1, 0x118, 0xf);
      DPP_ADD(s2, 0x118, 0xf); DPP_ADD(s3, 0x118, 0xf);
      DPP_ADD(s0, 0x142, 0xa); DPP_ADD(s1, 0x142, 0xa);
      DPP_ADD(s2, 0x142, 0xa); DPP_ADD(s3, 0x142, 0xa);
      DPP_ADD(s0, 0x143, 0xc); DPP_ADD(s1, 0x143, 0xc);
      DPP_ADD(s2, 0x143, 0xc); DPP_ADD(s3, 0x143, 0xc);
      s0 = __int_as_float(__builtin_amdgcn_readlane(__float_as_int(s0), 63));
      s1 = __int_as_float(__builtin_amdgcn_readlane(__float_as_int(s1), 63));
      s2 = __int_as_float(__builtin_amdgcn_readlane(__float_as_int(s2), 63));
      s3 = __int_as_float(__builtin_amdgcn_readlane(__float_as_int(s3), 63));

      float w3 = 2.f * __builtin_amdgcn_rcpf(rA3.w) * (x.w - s3);
      float s2c = fmaf(rA2.w, w3, s2);
      float w2 = 2.f * __builtin_amdgcn_rcpf(rA2.z) * (x.z - s2c);
      float s1c = fmaf(rA1.z, w2, fmaf(rA1.w, w3, s1));
      float w1 = 2.f * __builtin_amdgcn_rcpf(rA1.y) * (x.y - s1c);
      float s0c = fmaf(rA0.y, w1, fmaf(rA0.z, w2, fmaf(rA0.w, w3, s0)));
      float w0 = 2.f * __builtin_amdgcn_rcpf(rA0.x) * (x.x - s0c);
      if (lane == r4) { w.w = w3; w.z = w2; w.y = w1; w.x = w0; }

      if (!more) break;
      rowlen = nrl; base = nbs;
      rA0 = rB0; rA1 = rB1; rA2 = rB2; rA3 = rB3;
    }
  }

  u32 pw[4] = { pack_split(w.x), pack_split(w.y), pack_split(w.z), pack_split(w.w) };
  *(uint4*)(WtP + ((size_t)b * R_ + k) * R_ + 4 * lane) = *(uint4*)pw;
}

// ---------------------------------------------------------------------------
// K3: Q = E - V @ W via MFMA. grid (32, 2, 16), block 256 (4 waves 2x2).
// R13: DOUBLE-BUFFERED DMA + counted vmcnt (T3/T4). Per iter:
//   vmcnt(8)  -> drains current tile's 8 DMAs, leaves next tile's 8 in flight
//   s_barrier -> every wave drained its own DMAs => whole tile visible
//   frag reads; lgkmcnt(0)+s_barrier (buffer-reuse safety)
//   clamped refill issue (tile+2, same 8-op count -> vmcnt invariant exact)
//   MFMAs (DMA flies under them AND under the next iter's read phase)
// ---------------------------------------------------------------------------
__global__ __launch_bounds__(256) void final_kernel(const float* __restrict__ param,
                                                    const u32* __restrict__ WtP,
                                                    float* __restrict__ Q) {
  const int b  = blockIdx.z;
  const int n0 = blockIdx.x * 128;
  const int k0 = blockIdx.y * 128;
  const float* __restrict__ Pb = param + (size_t)b * N_ * R_;
  const u32* __restrict__ Wb = WtP + (size_t)b * R_ * R_;
  float* __restrict__ Qb = Q + (size_t)b * N_ * R_;

  __shared__ float VA2[2][128][32];   // raw fp32 V tiles (swizzled 16B chunks)
  __shared__ u32   WB2[2][128][32];   // packed split-bf16 W tiles

  const int t = threadIdx.x;
  const int lane = t & 63, wv = t >> 6;
  const int wr = wv >> 1, wc = wv & 1;
  const int l15 = lane & 15, q = lane >> 4;
  const int rsub = lane >> 3;
  const int csub = lane & 7;
  const int chsw = csub ^ rsub;

  f32x4 acc[4][4];
#pragma unroll
  for (int i = 0; i < 4; ++i)
#pragma unroll
    for (int j = 0; j < 4; ++j) acc[i][j] = (f32x4){0.f, 0.f, 0.f, 0.f};

  auto issue = [&](int jb, int p) {
#pragma unroll
    for (int c = 0; c < 4; ++c) {
      int rbase = 32 * c + 8 * wv;
      int row   = rbase + rsub;
      async_cp16(&VA2[p][rbase][0], &Pb[(size_t)(n0 + row) * R_ + jb + 4 * chsw]);
      async_cp16(&WB2[p][rbase][0], &Wb[(size_t)(k0 + row) * R_ + jb + 4 * chsw]);
    }
  };

  const int jend = k0 + 128;          // 128 or 256
  const int last = jend - 32;
  issue(0, 0);
  issue(32, 1);                        // jend >= 128 always
  for (int jb = 0; jb < jend; jb += 32) {
    const int p = (jb >> 5) & 1;

    asm volatile("s_waitcnt vmcnt(8)" ::: "memory");  // current tile landed
    __builtin_amdgcn_s_barrier();
    __builtin_amdgcn_sched_barrier(0);

    if (n0 < 256 && n0 <= jb + 31) {   // triangle fixup (block-uniform cond)
#pragma unroll
      for (int m = 0; m < 16; ++m) {
        int idx = t + 256 * m;
        int row = idx >> 5;
        int j   = idx & 31;
        int n   = n0 + row;
        int gj  = jb + j;
        if (n <= gj)
          VA2[p][row][(((j >> 2) ^ (row & 7)) << 2) + (j & 3)] = (n == gj) ? 1.f : 0.f;
      }
      asm volatile("s_waitcnt lgkmcnt(0)" ::: "memory");
      __builtin_amdgcn_s_barrier();
      __builtin_amdgcn_sched_barrier(0);
    }

    bf16x8 Ah[4], Al[4], Bh[4], Bl[4];
#pragma unroll
    for (int mt = 0; mt < 4; ++mt) {
      int row = 64 * wr + 16 * mt + l15;
      read_frag_f(&VA2[p][row][0], row, 2 * q, Ah[mt], Al[mt]);
    }
#pragma unroll
    for (int nt = 0; nt < 4; ++nt) {
      int krow = 64 * wc + 16 * nt + l15;
      read_frag(&WB2[p][krow][0], krow, 2 * q, Bh[nt], Bl[nt]);
    }

    asm volatile("s_waitcnt lgkmcnt(0)" ::: "memory");  // reads retired
    __builtin_amdgcn_s_barrier();                       // buffer p reusable
    __builtin_amdgcn_sched_barrier(0);

    int jn = jb + 64; if (jn > last) jn = last;         // clamp keeps count
    issue(jn, p);                                       // refill buffer p

#pragma unroll
    for (int nt = 0; nt < 4; ++nt)
#pragma unroll
      for (int mt = 0; mt < 4; ++mt)
        acc[mt][nt] = mm3(Ah[mt], Al[mt], Bh[nt], Bl[nt], acc[mt][nt]);
  }

  asm volatile("s_waitcnt vmcnt(0)" ::: "memory");      // drain before overlay
  __syncthreads();

  // epilogue: coalesced stores via LDS (overlay on VA2)
  float* Ep = (float*)&VA2[0][0][0];
  const int erow = t >> 3;
  const int ec16 = (t & 7) * 16;
#pragma unroll
  for (int mt = 0; mt < 4; ++mt) {
    __syncthreads();
#pragma unroll
    for (int nt = 0; nt < 4; ++nt) {
      int kcol = k0 + 64 * wc + 16 * nt + l15;
#pragma unroll
      for (int r = 0; r < 4; ++r) {
        int nrow = n0 + 64 * wr + 16 * mt + 4 * q + r;
        int lrow = 16 * wr + 4 * q + r;
        Ep[lrow * 132 + 64 * wc + 16 * nt + l15] =
            ((nrow == kcol) ? 1.f : 0.f) - acc[mt][nt][r];
      }
    }
    __syncthreads();
    int grow = n0 + 64 * (erow >> 4) + 16 * mt + (erow & 15);
#pragma unroll
    for (int s = 0; s < 4; ++s) {
      float4 v = *(const float4*)&Ep[erow * 132 + ec16 + 4 * s];
      *(float4*)&Qb[(size_t)grow * R_ + k0 + ec16 + 4 * s] = v;
    }
  }
}

extern "C" void kernel_launch(void* const* d_in, const int* in_sizes, int n_in,
                              void* d_out, int out_size, void* d_ws, size_t ws_size,
                              hipStream_t stream) {
  const float* param = (const float*)d_in[0];
  float* Q  = (float*)d_out;
  // d_out during pipeline: SP = 16 chunks x 16 b x 256x256 fp32 (64 MB);
  // reduce folds chunks 1..15 into chunk 0 (= S) over the 3-tile region;
  // final overwrites everything with Q.
  float* SP = Q;
  float* S  = Q;
  u32*   WtP = (u32*)d_ws;  // 4 MB packed split-bf16 W^T

  gram_kernel<<<dim3(3, 16, B_), 256, 0, stream>>>(param, SP);
  reduce_kernel<<<dim3(48, 16), 256, 0, stream>>>(SP);
  solve_kernel<<<dim3(256), 1024, 133120, stream>>>(param, S, WtP);
  final_kernel<<<dim3(32, 2, B_), 256, 0, stream>>>(param, WtP, Q);
}

// Round 14
// 133.555 us; speedup vs baseline: 1.0472x; 1.0472x over previous
//
#include <hip/hip_runtime.h>
#include <stdint.h>

#define B_ 16
#define N_ 4096
#define R_ 256

typedef short bf16x8 __attribute__((ext_vector_type(8)));
typedef float f32x4 __attribute__((ext_vector_type(4)));
typedef uint32_t u32;

// V[b,n,i] = (n==i) ? 1 : (n>i ? param[b,n,i] : 0)
// Pipeline: S = V^T V (split-bf16 MFMA partials, packed-u32 LDS staging) ->
// reduce (tile region, in place) -> solve (LDS-resident triangular S, DPP
// wave-sums; W written as RNE bf16 pairs) -> Q = E - V W (MFMA: V split
// hi+lo x W bf16 = 2 MFMAs/product; W tile 8 KB, no unpack).
//
// Error budget: threshold 2e-2, R13 absmax 1.22e-4. W-as-bf16 (RNE) adds
// <= ||v_row||*||w_col||*2^-10 ~ 2.5e-4 to Q. S keeps full split (tau
// errors amplify systematically).

__device__ __forceinline__ u32 rne16(float x) {
  u32 u = __float_as_uint(x);
  return (u + 0x7fffu + ((u >> 16) & 1u)) >> 16;
}

__device__ __forceinline__ u32 pack_split(float x) {
  u32 u = __float_as_uint(x);
  u32 h = u & 0xffff0000u;
  float l = x - __uint_as_float(h);
  return h | (__float_as_uint(l) >> 16);
}

__device__ __forceinline__ void unpack8(const u32* w, bf16x8& hi, bf16x8& lo) {
  union { u32 u[4]; bf16x8 v; } H, L;
#pragma unroll
  for (int i = 0; i < 4; ++i) {
    u32 a = w[2 * i], b = w[2 * i + 1];
    H.u[i] = (a >> 16) | (b & 0xffff0000u);
    L.u[i] = (a & 0xffffu) | (b << 16);
  }
  hi = H.v; lo = L.v;
}

// Packed-u32 frag read from swizzled [row][32-word] LDS tile.
__device__ __forceinline__ void read_frag(const u32* rowbase, int row, int q2,
                                          bf16x8& hi, bf16x8& lo) {
  u32 w[8];
  const int s = row & 7;
  *(uint4*)&w[0] = *(const uint4*)(rowbase + (((q2    ) ^ s) << 2));
  *(uint4*)&w[4] = *(const uint4*)(rowbase + (((q2 + 1) ^ s) << 2));
  unpack8(w, hi, lo);
}

// Raw-fp32 frag read + on-the-fly truncating split.
__device__ __forceinline__ void read_frag_f(const float* rowbase, int row, int q2,
                                            bf16x8& hi, bf16x8& lo) {
  float w[8];
  const int s = row & 7;
  *(float4*)&w[0] = *(const float4*)(rowbase + (((q2    ) ^ s) << 2));
  *(float4*)&w[4] = *(const float4*)(rowbase + (((q2 + 1) ^ s) << 2));
  union { u32 u[4]; bf16x8 v; } H, L;
#pragma unroll
  for (int i = 0; i < 4; ++i) {
    u32 a = __float_as_uint(w[2 * i]);
    u32 b = __float_as_uint(w[2 * i + 1]);
    u32 ah = a & 0xffff0000u, bh = b & 0xffff0000u;
    float la = w[2 * i]     - __uint_as_float(ah);
    float lb = w[2 * i + 1] - __uint_as_float(bh);
    H.u[i] = (a >> 16) | bh;
    L.u[i] = (__float_as_uint(la) >> 16) | (__float_as_uint(lb) & 0xffff0000u);
  }
  hi = H.v; lo = L.v;
}

__device__ __forceinline__ f32x4 mm3(bf16x8 ah, bf16x8 al, bf16x8 bh, bf16x8 bl,
                                     f32x4 c) {
  c = __builtin_amdgcn_mfma_f32_16x16x32_bf16(al, bh, c, 0, 0, 0);
  c = __builtin_amdgcn_mfma_f32_16x16x32_bf16(ah, bl, c, 0, 0, 0);
  c = __builtin_amdgcn_mfma_f32_16x16x32_bf16(ah, bh, c, 0, 0, 0);
  return c;
}

typedef __attribute__((address_space(1))) const u32* gas_p;
typedef __attribute__((address_space(3))) u32* las_p;
__device__ __forceinline__ void async_cp16(void* lds, const void* g) {
  __builtin_amdgcn_global_load_lds((gas_p)g, (las_p)lds, 16, 0, 0);
}

// ---------------------------------------------------------------------------
// K1: partial Gram via MFMA (R12/R10 proven form, unchanged).
// ---------------------------------------------------------------------------
__global__ __launch_bounds__(256) void gram_kernel(const float* __restrict__ param,
                                                   float* __restrict__ SP) {
  const int tile = blockIdx.x, chunk = blockIdx.y, b = blockIdx.z;
  const int j0 = (tile == 2) ? 128 : 0;
  const int k0 = (tile == 0) ? 0 : 128;
  const float* __restrict__ P = param + (size_t)b * N_ * R_;

  __shared__ u32 VT[256][32];

  const int t = threadIdx.x;
  const int lane = t & 63, wv = t >> 6;
  const int wr = wv >> 1, wc = wv & 1;
  const int l15 = lane & 15, q = lane >> 4;
  const int bbase = (tile == 1) ? 128 : 0;

  f32x4 acc[4][4];
#pragma unroll
  for (int i = 0; i < 4; ++i)
#pragma unroll
    for (int j = 0; j < 4; ++j) acc[i][j] = (f32x4){0.f, 0.f, 0.f, 0.f};

  const int nb = chunk * 256;
  const int ns = (nb > k0) ? nb : k0;
  const int ne = nb + 256;

  float ld[32];

  const int ct1 = t;
  const int ct0 = t & 127;
  const int gc0 = j0 + ct0;
  const int hb  = t >> 7;

  auto do_load = [&](int n0) {
    if (tile == 1) {
#pragma unroll
      for (int ri = 0; ri < 8; ++ri)
#pragma unroll
        for (int s = 0; s < 4; ++s)
          ld[4 * ri + s] = P[(size_t)(n0 + 4 * ri + s) * R_ + ct1];
    } else {
#pragma unroll
      for (int ri = 0; ri < 4; ++ri)
#pragma unroll
        for (int s = 0; s < 4; ++s)
          ld[4 * ri + s] = P[(size_t)(n0 + 4 * (2 * ri + hb) + s) * R_ + gc0];
    }
  };

  auto do_write = [&](int n0) {
    if (tile == 1) {
#pragma unroll
      for (int ri = 0; ri < 8; ++ri) {
        u32 qw[4];
#pragma unroll
        for (int s = 0; s < 4; ++s) {
          int n = n0 + 4 * ri + s;
          float v = (n == ct1) ? 1.f : ((n > ct1) ? ld[4 * ri + s] : 0.f);
          qw[s] = pack_split(v);
        }
        *(uint4*)&VT[ct1][((ri ^ (ct1 & 7)) << 2)] = *(uint4*)qw;
      }
    } else {
#pragma unroll
      for (int ri = 0; ri < 4; ++ri) {
        int ch = 2 * ri + hb;
        u32 qw[4];
#pragma unroll
        for (int s = 0; s < 4; ++s) {
          int n = n0 + 4 * ch + s;
          float v = (n == gc0) ? 1.f : ((n > gc0) ? ld[4 * ri + s] : 0.f);
          qw[s] = pack_split(v);
        }
        *(uint4*)&VT[ct0][((ch ^ (ct0 & 7)) << 2)] = *(uint4*)qw;
      }
    }
  };

  do_load(ns);
  for (int n0 = ns; n0 < ne; n0 += 32) {
    do_write(n0);
    __syncthreads();
    if (n0 + 32 < ne) do_load(n0 + 32);

    bf16x8 Ah[4], Al[4];
#pragma unroll
    for (int mt = 0; mt < 4; ++mt) {
      int row = 64 * wr + 16 * mt + l15;
      read_frag(&VT[row][0], row, 2 * q, Ah[mt], Al[mt]);
    }
#pragma unroll
    for (int nt = 0; nt < 4; ++nt) {
      int brow = bbase + 64 * wc + 16 * nt + l15;
      bf16x8 bh, bl;
      read_frag(&VT[brow][0], brow, 2 * q, bh, bl);
#pragma unroll
      for (int mt = 0; mt < 4; ++mt)
        acc[mt][nt] = mm3(Ah[mt], Al[mt], bh, bl, acc[mt][nt]);
    }
    __syncthreads();
  }

  float* Sp = SP + (size_t)(chunk * 16 + b) * (R_ * R_);
#pragma unroll
  for (int mt = 0; mt < 4; ++mt)
#pragma unroll
    for (int nt = 0; nt < 4; ++nt) {
      int jj = j0 + 64 * wr + 16 * mt + 4 * q;
      int kk = k0 + 64 * wc + 16 * nt + l15;
#pragma unroll
      for (int r = 0; r < 4; ++r)
        Sp[(size_t)(jj + r) * R_ + kk] = acc[mt][nt][r];
    }
}

// ---------------------------------------------------------------------------
// reduce: sum 16 chunks into chunk 0, tile region only. grid (48, 16).
// ---------------------------------------------------------------------------
__global__ __launch_bounds__(256) void reduce_kernel(float* __restrict__ SP) {
  const int b = blockIdx.y;
  int j = blockIdx.x * 256 + threadIdx.x;
  int r, c4;
  if (j < 8192) { r = j >> 6; c4 = j & 63; }
  else { int jj = j - 8192; r = 128 + (jj >> 5); c4 = 32 + (jj & 31); }
  size_t idx = (size_t)b * 16384 + (size_t)r * 64 + c4;
  float4* sp = (float4*)SP;
  float4 a = sp[idx];
#pragma unroll
  for (int c = 1; c < 16; ++c) {
    float4 v = sp[idx + (size_t)c * 262144];
    a.x += v.x; a.y += v.y; a.z += v.z; a.w += v.w;
  }
  sp[idx] = a;
}

#define DPP_ADD(v, ctrl, rmask)                                              \
  v += __int_as_float(__builtin_amdgcn_update_dpp(                           \
      0, __float_as_int(v), ctrl, rmask, 0xf, true))

// ---------------------------------------------------------------------------
// K2: wave-per-column backward substitution over LDS-resident triangular S
// (R12 core). Epilogue now emits W as RNE bf16 PAIRS:
// Whg[b][k][p] = bf16(W[2p][k]) | bf16(W[2p+1][k])<<16   (2 MB total).
// ---------------------------------------------------------------------------
__global__ __launch_bounds__(1024) void solve_kernel(const float* __restrict__ param,
                                                     const float* __restrict__ S,
                                                     u32* __restrict__ Whg) {
  extern __shared__ float tri[];
  const int t    = threadIdx.x;
  const int lane = t & 63;
  const int wave = t >> 6;
  const int b    = blockIdx.x >> 4;
  const int jg   = blockIdx.x & 15;
  const int k    = jg + 16 * wave;
  const float* __restrict__ Sb = S + (size_t)b * R_ * R_;
  const float* __restrict__ Pb = param + (size_t)b * N_ * R_;

  float4 x = *(const float4*)(Pb + (size_t)k * R_ + 4 * lane);
  {
    int c0 = 4 * lane;
    x.x = (c0     == k) ? 1.f : ((c0     < k) ? x.x : 0.f);
    x.y = (c0 + 1 == k) ? 1.f : ((c0 + 1 < k) ? x.y : 0.f);
    x.z = (c0 + 2 == k) ? 1.f : ((c0 + 2 < k) ? x.z : 0.f);
    x.w = (c0 + 3 == k) ? 1.f : ((c0 + 3 < k) ? x.w : 0.f);
  }

  const float4* S4 = (const float4*)Sb;
#pragma unroll
  for (int m = 0; m < 16; ++m) {
    int idx = t + 1024 * m;
    int r  = idx >> 6;
    int c4 = idx & 63;
    int g  = r >> 2;
    if (c4 >= g) {
      float4 v = S4[idx];
      int rowlen = 256 - 4 * g;
      int addr = 1024 * g - 8 * g * (g - 1) + (r & 3) * rowlen + 4 * (c4 - g);
      *(float4*)&tri[addr] = v;
    }
  }
  __syncthreads();

  float4 w = make_float4(0.f, 0.f, 0.f, 0.f);
  const int k4 = k >> 2;
  int rowlen = 256 - 4 * k4;
  int base   = 1024 * k4 - 8 * k4 * (k4 - 1);

  {
    const float* rb = tri + base + 4 * lane - 4 * k4;
    float4 rA0 = *(const float4*)(rb);
    float4 rA1 = *(const float4*)(rb + rowlen);
    float4 rA2 = *(const float4*)(rb + 2 * rowlen);
    float4 rA3 = *(const float4*)(rb + 3 * rowlen);

    for (int r4 = k4;; --r4) {
      const bool more = (r4 > 0);

      float s0 = fmaf(rA0.x, w.x, fmaf(rA0.y, w.y, fmaf(rA0.z, w.z, rA0.w * w.w)));
      float s1 = fmaf(rA1.x, w.x, fmaf(rA1.y, w.y, fmaf(rA1.z, w.z, rA1.w * w.w)));
      float s2 = fmaf(rA2.x, w.x, fmaf(rA2.y, w.y, fmaf(rA2.z, w.z, rA2.w * w.w)));
      float s3 = fmaf(rA3.x, w.x, fmaf(rA3.y, w.y, fmaf(rA3.z, w.z, rA3.w * w.w)));

      float4 rB0, rB1, rB2, rB3;
      int nrl = rowlen, nbs = base;
      if (more) {
        nrl = rowlen + 4;
        nbs = base - 4 * nrl;
        const float* rbn = tri + nbs + 4 * lane - 4 * (r4 - 1);
        rB0 = *(const float4*)(rbn);
        rB1 = *(const float4*)(rbn + nrl);
        rB2 = *(const float4*)(rbn + 2 * nrl);
        rB3 = *(const float4*)(rbn + 3 * nrl);
      }
      __builtin_amdgcn_sched_barrier(0);

      DPP_ADD(s0, 0x111, 0xf); DPP_ADD(s1, 0x111, 0xf);
      DPP_ADD(s2, 0x111, 0xf); DPP_ADD(s3, 0x111, 0xf);
      DPP_ADD(s0, 0x112, 0xf); DPP_ADD(s1, 0x112, 0xf);
      DPP_ADD(s2, 0x112, 0xf); DPP_ADD(s3, 0x112, 0xf);
      DPP_ADD(s0, 0x114, 0xf); DPP_ADD(s1, 0x114, 0xf);
      DPP_ADD(s2, 0x114, 0xf); DPP_ADD(s3, 0x114, 0xf);
      DPP_ADD(s0, 0x118, 0xf); DPP_ADD(s1, 0x118, 0xf);
      DPP_ADD(s2, 0x118, 0xf); DPP_ADD(s3, 0x118, 0xf);
      DPP_ADD(s0, 0x142, 0xa); DPP_ADD(s1, 0x142, 0xa);
      DPP_ADD(s2, 0x142, 0xa); DPP_ADD(s3, 0x142, 0xa);
      DPP_ADD(s0, 0x143, 0xc); DPP_ADD(s1, 0x143, 0xc);
      DPP_ADD(s2, 0x143, 0xc); DPP_ADD(s3, 0x143, 0xc);
      s0 = __int_as_float(__builtin_amdgcn_readlane(__float_as_int(s0), 63));
      s1 = __int_as_float(__builtin_amdgcn_readlane(__float_as_int(s1), 63));
      s2 = __int_as_float(__builtin_amdgcn_readlane(__float_as_int(s2), 63));
      s3 = __int_as_float(__builtin_amdgcn_readlane(__float_as_int(s3), 63));

      float w3 = 2.f * __builtin_amdgcn_rcpf(rA3.w) * (x.w - s3);
      float s2c = fmaf(rA2.w, w3, s2);
      float w2 = 2.f * __builtin_amdgcn_rcpf(rA2.z) * (x.z - s2c);
      float s1c = fmaf(rA1.z, w2, fmaf(rA1.w, w3, s1));
      float w1 = 2.f * __builtin_amdgcn_rcpf(rA1.y) * (x.y - s1c);
      float s0c = fmaf(rA0.y, w1, fmaf(rA0.z, w2, fmaf(rA0.w, w3, s0)));
      float w0 = 2.f * __builtin_amdgcn_rcpf(rA0.x) * (x.x - s0c);
      if (lane == r4) { w.w = w3; w.z = w2; w.y = w1; w.x = w0; }

      if (!more) break;
      rowlen = nrl; base = nbs;
      rA0 = rB0; rA1 = rB1; rA2 = rB2; rA3 = rB3;
    }
  }

  // W as RNE bf16 pairs: lane holds j = 4L..4L+3 of column k.
  u32 p0 = rne16(w.x) | (rne16(w.y) << 16);
  u32 p1 = rne16(w.z) | (rne16(w.w) << 16);
  *(uint2*)(Whg + ((size_t)b * R_ + k) * 128 + 2 * lane) = make_uint2(p0, p1);
}

// ---------------------------------------------------------------------------
// K3: Q = E - V @ W via MFMA. grid (32, 2, 16), block 256 (4 waves 2x2).
// R14: W is bf16 (RNE) -> 2 MFMAs/product, W tile 8 KB (1 b128/frag, no
// unpack). V: fp32 DMA + split-on-read (exact). LDS 24 KB -> ~5 blocks/CU.
// Long blocks (k0=128, 8 iters) dispatch first (y==0).
// ---------------------------------------------------------------------------
__global__ __launch_bounds__(256) void final_kernel(const float* __restrict__ param,
                                                    const u32* __restrict__ Whg,
                                                    float* __restrict__ Q) {
  const int b  = blockIdx.z;
  const int n0 = blockIdx.x * 128;
  const int k0 = (blockIdx.y == 0) ? 128 : 0;   // long blocks first
  const float* __restrict__ Pb = param + (size_t)b * N_ * R_;
  const u32* __restrict__ Wb = Whg + (size_t)b * R_ * 128;
  float* __restrict__ Qb = Q + (size_t)b * N_ * R_;

  __shared__ struct {
    float VAf[128][32];   // raw fp32 V tile (swizzled 16B chunks, chunk^row&7)
    u32   WBh[128][16];   // bf16-pair W tile (chunk^((row>>1)&3))
  } sm;

  const int t = threadIdx.x;
  const int lane = t & 63, wv = t >> 6;
  const int wr = wv >> 1, wc = wv & 1;
  const int l15 = lane & 15, q = lane >> 4;
  const int rsub = lane >> 3;     // V-DMA: row-within-8
  const int csub = lane & 7;      // V-DMA: chunk
  const int wrow4 = lane >> 2;    // W-DMA: row-within-16
  const int wch   = lane & 3;     // W-DMA: chunk

  f32x4 acc[4][4];
#pragma unroll
  for (int i = 0; i < 4; ++i)
#pragma unroll
    for (int j = 0; j < 4; ++j) acc[i][j] = (f32x4){0.f, 0.f, 0.f, 0.f};

  auto issue = [&](int jb) {
#pragma unroll
    for (int c = 0; c < 4; ++c) {           // V: 4 calls x 8 rows
      int rbase = 32 * c + 8 * wv;
      int row   = rbase + rsub;
      async_cp16(&sm.VAf[rbase][0],
                 &Pb[(size_t)(n0 + row) * R_ + jb + 4 * (csub ^ (row & 7))]);
    }
#pragma unroll
    for (int c = 0; c < 2; ++c) {           // Wh: 2 calls x 16 rows
      int rbase = 16 * (wv + 4 * c);
      int row   = rbase + wrow4;
      async_cp16(&sm.WBh[rbase][0],
                 &Wb[(size_t)(k0 + row) * 128 + (jb >> 1) +
                     4 * (wch ^ ((row >> 1) & 3))]);
    }
  };

  const int jend = k0 + 128;
  issue(0);
  for (int jb = 0; jb < jend; jb += 32) {
    __syncthreads();   // drains DMA -> tile visible

    if (n0 < 256 && n0 <= jb + 31) {   // triangle fixup (block-uniform cond)
#pragma unroll
      for (int m = 0; m < 16; ++m) {
        int idx = t + 256 * m;
        int row = idx >> 5;
        int j   = idx & 31;
        int n   = n0 + row;
        int gj  = jb + j;
        if (n <= gj)
          sm.VAf[row][(((j >> 2) ^ (row & 7)) << 2) + (j & 3)] = (n == gj) ? 1.f : 0.f;
      }
      __syncthreads();
    }

    bf16x8 Ah[4], Al[4], Bh[4];
#pragma unroll
    for (int mt = 0; mt < 4; ++mt) {
      int row = 64 * wr + 16 * mt + l15;
      read_frag_f(&sm.VAf[row][0], row, 2 * q, Ah[mt], Al[mt]);
    }
#pragma unroll
    for (int nt = 0; nt < 4; ++nt) {
      int krow = 64 * wc + 16 * nt + l15;
      union { uint4 u; bf16x8 v; } X;
      X.u = *(const uint4*)(&sm.WBh[krow][(q ^ ((krow >> 1) & 3)) << 2]);
      Bh[nt] = X.v;
    }
    __syncthreads();   // LDS free for next tile's DMA

    if (jb + 32 < jend) issue(jb + 32);  // flies under MFMA phase

#pragma unroll
    for (int nt = 0; nt < 4; ++nt)
#pragma unroll
      for (int mt = 0; mt < 4; ++mt) {
        acc[mt][nt] = __builtin_amdgcn_mfma_f32_16x16x32_bf16(
            Al[mt], Bh[nt], acc[mt][nt], 0, 0, 0);
        acc[mt][nt] = __builtin_amdgcn_mfma_f32_16x16x32_bf16(
            Ah[mt], Bh[nt], acc[mt][nt], 0, 0, 0);
      }
  }

  __syncthreads();

  // epilogue: coalesced stores via LDS (overlay on sm; needs 16.9 KB <= 24 KB)
  float* Ep = (float*)&sm;
  const int erow = t >> 3;
  const int ec16 = (t & 7) * 16;
#pragma unroll
  for (int mt = 0; mt < 4; ++mt) {
    __syncthreads();
#pragma unroll
    for (int nt = 0; nt < 4; ++nt) {
      int kcol = k0 + 64 * wc + 16 * nt + l15;
#pragma unroll
      for (int r = 0; r < 4; ++r) {
        int nrow = n0 + 64 * wr + 16 * mt + 4 * q + r;
        int lrow = 16 * wr + 4 * q + r;
        Ep[lrow * 132 + 64 * wc + 16 * nt + l15] =
            ((nrow == kcol) ? 1.f : 0.f) - acc[mt][nt][r];
      }
    }
    __syncthreads();
    int grow = n0 + 64 * (erow >> 4) + 16 * mt + (erow & 15);
#pragma unroll
    for (int s = 0; s < 4; ++s) {
      float4 v = *(const float4*)&Ep[erow * 132 + ec16 + 4 * s];
      *(float4*)&Qb[(size_t)grow * R_ + k0 + ec16 + 4 * s] = v;
    }
  }
}

extern "C" void kernel_launch(void* const* d_in, const int* in_sizes, int n_in,
                              void* d_out, int out_size, void* d_ws, size_t ws_size,
                              hipStream_t stream) {
  const float* param = (const float*)d_in[0];
  float* Q  = (float*)d_out;
  // d_out during pipeline: SP = 16 chunks x 16 b x 256x256 fp32 (64 MB);
  // reduce folds chunks 1..15 into chunk 0 (= S) over the 3-tile region;
  // final overwrites everything with Q.
  float* SP = Q;
  float* S  = Q;
  u32*   Whg = (u32*)d_ws;  // 2 MB: RNE bf16 pairs of W^T

  gram_kernel<<<dim3(3, 16, B_), 256, 0, stream>>>(param, SP);
  reduce_kernel<<<dim3(48, 16), 256, 0, stream>>>(SP);
  solve_kernel<<<dim3(256), 1024, 133120, stream>>>(param, S, Whg);
  final_kernel<<<dim3(32, 2, B_), 256, 0, stream>>>(param, Whg, Q);
}

// Round 15
// 130.631 us; speedup vs baseline: 1.0706x; 1.0224x over previous
//
#include <hip/hip_runtime.h>
#include <stdint.h>

#define B_ 16
#define N_ 4096
#define R_ 256

typedef short bf16x8 __attribute__((ext_vector_type(8)));
typedef float f32x4 __attribute__((ext_vector_type(4)));
typedef uint32_t u32;

// V[b,n,i] = (n==i) ? 1 : (n>i ? param[b,n,i] : 0)
// Pipeline: S = V^T V (split-bf16 MFMA partials; PRE-SPLIT bf16-pair LDS ->
// zero unpack at frag read) -> reduce (tile region, in place) -> solve
// (LDS-resident triangular S, DPP wave-sums; W as RNE bf16 pairs) ->
// Q = E - V W (V split hi+lo x W bf16 = 2 MFMAs/product).
//
// Error budget: threshold 2e-2, measured absmax 3.9e-3 (W-bf16 dominated).
// This round is bit-identical to R14 (layout change only).

__device__ __forceinline__ u32 rne16(float x) {
  u32 u = __float_as_uint(x);
  return (u + 0x7fffu + ((u >> 16) & 1u)) >> 16;
}

__device__ __forceinline__ u32 pack_split(float x) {
  u32 u = __float_as_uint(x);
  u32 h = u & 0xffff0000u;
  float l = x - __uint_as_float(h);
  return h | (__float_as_uint(l) >> 16);
}

// Pair packers: hi/lo bf16 (truncating split, identical values to pack_split).
__device__ __forceinline__ void pair_split(float x0, float x1, u32& hp, u32& lp) {
  u32 u0 = __float_as_uint(x0), u1 = __float_as_uint(x1);
  u32 h0 = u0 & 0xffff0000u, h1 = u1 & 0xffff0000u;
  float l0 = x0 - __uint_as_float(h0);
  float l1 = x1 - __uint_as_float(h1);
  hp = (h0 >> 16) | h1;
  lp = (__float_as_uint(l0) >> 16) | (__float_as_uint(l1) & 0xffff0000u);
}

// Frag read from pre-split pair tile: hi = chunk q, lo = chunk q+4. No VALU.
__device__ __forceinline__ void read_frag2(const u32* rowbase, int row, int q,
                                           bf16x8& hi, bf16x8& lo) {
  const int s = row & 7;
  union { uint4 u; bf16x8 v; } H, L;
  H.u = *(const uint4*)(rowbase + (((q    ) ^ s) << 2));
  L.u = *(const uint4*)(rowbase + (((q + 4) ^ s) << 2));
  hi = H.v; lo = L.v;
}

// Raw-fp32 frag read + on-the-fly truncating split (final_kernel's V).
__device__ __forceinline__ void read_frag_f(const float* rowbase, int row, int q2,
                                            bf16x8& hi, bf16x8& lo) {
  float w[8];
  const int s = row & 7;
  *(float4*)&w[0] = *(const float4*)(rowbase + (((q2    ) ^ s) << 2));
  *(float4*)&w[4] = *(const float4*)(rowbase + (((q2 + 1) ^ s) << 2));
  union { u32 u[4]; bf16x8 v; } H, L;
#pragma unroll
  for (int i = 0; i < 4; ++i) {
    u32 a = __float_as_uint(w[2 * i]);
    u32 b = __float_as_uint(w[2 * i + 1]);
    u32 ah = a & 0xffff0000u, bh = b & 0xffff0000u;
    float la = w[2 * i]     - __uint_as_float(ah);
    float lb = w[2 * i + 1] - __uint_as_float(bh);
    H.u[i] = (a >> 16) | bh;
    L.u[i] = (__float_as_uint(la) >> 16) | (__float_as_uint(lb) & 0xffff0000u);
  }
  hi = H.v; lo = L.v;
}

__device__ __forceinline__ f32x4 mm3(bf16x8 ah, bf16x8 al, bf16x8 bh, bf16x8 bl,
                                     f32x4 c) {
  c = __builtin_amdgcn_mfma_f32_16x16x32_bf16(al, bh, c, 0, 0, 0);
  c = __builtin_amdgcn_mfma_f32_16x16x32_bf16(ah, bl, c, 0, 0, 0);
  c = __builtin_amdgcn_mfma_f32_16x16x32_bf16(ah, bh, c, 0, 0, 0);
  return c;
}

typedef __attribute__((address_space(1))) const u32* gas_p;
typedef __attribute__((address_space(3))) u32* las_p;
__device__ __forceinline__ void async_cp16(void* lds, const void* g) {
  __builtin_amdgcn_global_load_lds((gas_p)g, (las_p)lds, 16, 0, 0);
}

// ---------------------------------------------------------------------------
// K1: partial Gram via MFMA. grid (3 tiles, 16 n-chunks of 256, 16 b), 256 thr.
// R15: LDS = pre-split pair tile VT2[256 rows][32 words]: words 0-15 hi-pairs,
// 16-31 lo-pairs, 16B chunks swizzled c^(row&7). Frag read = 2 ds_read_b128,
// ZERO unpack VALU (R11 lesson: pay conversion once at produce, not at
// consume). Hi/lo values + MFMA order bit-identical to R14.
// ---------------------------------------------------------------------------
__global__ __launch_bounds__(256) void gram_kernel(const float* __restrict__ param,
                                                   float* __restrict__ SP) {
  const int tile = blockIdx.x, chunk = blockIdx.y, b = blockIdx.z;
  const int j0 = (tile == 2) ? 128 : 0;
  const int k0 = (tile == 0) ? 0 : 128;
  const float* __restrict__ P = param + (size_t)b * N_ * R_;

  __shared__ u32 VT2[256][32];

  const int t = threadIdx.x;
  const int lane = t & 63, wv = t >> 6;
  const int wr = wv >> 1, wc = wv & 1;
  const int l15 = lane & 15, q = lane >> 4;
  const int bbase = (tile == 1) ? 128 : 0;

  f32x4 acc[4][4];
#pragma unroll
  for (int i = 0; i < 4; ++i)
#pragma unroll
    for (int j = 0; j < 4; ++j) acc[i][j] = (f32x4){0.f, 0.f, 0.f, 0.f};

  const int nb = chunk * 256;
  const int ns = (nb > k0) ? nb : k0;
  const int ne = nb + 256;

  float ld[32];

  const int ct1 = t;
  const int ct0 = t & 127;
  const int gc0 = j0 + ct0;
  const int hb  = t >> 7;

  auto do_load = [&](int n0) {
    if (tile == 1) {
#pragma unroll
      for (int ri = 0; ri < 8; ++ri)
#pragma unroll
        for (int s = 0; s < 4; ++s)
          ld[4 * ri + s] = P[(size_t)(n0 + 4 * ri + s) * R_ + ct1];
    } else {
#pragma unroll
      for (int ri = 0; ri < 4; ++ri)
#pragma unroll
        for (int s = 0; s < 4; ++s)
          ld[4 * ri + s] = P[(size_t)(n0 + 4 * (2 * ri + hb) + s) * R_ + gc0];
    }
  };

  auto do_write = [&](int n0) {
    if (tile == 1) {
      // thread owns full column ct1; elements e = ld[e] (e = n - n0).
      const int sw = ct1 & 7;
#pragma unroll
      for (int c = 0; c < 4; ++c) {          // chunk c: elements 8c..8c+7
        u32 hw[4], lw[4];
#pragma unroll
        for (int p = 0; p < 4; ++p) {        // pair p: elems 8c+2p, 8c+2p+1
          int e0 = 8 * c + 2 * p;
          int n0e = n0 + e0;
          float x0 = ld[e0], x1 = ld[e0 + 1];
          x0 = (n0e     == ct1) ? 1.f : ((n0e     > ct1) ? x0 : 0.f);
          x1 = (n0e + 1 == ct1) ? 1.f : ((n0e + 1 > ct1) ? x1 : 0.f);
          pair_split(x0, x1, hw[p], lw[p]);
        }
        *(uint4*)&VT2[ct1][((c    ) ^ sw) << 2] = *(uint4*)hw;
        *(uint4*)&VT2[ct1][((c + 4) ^ sw) << 2] = *(uint4*)lw;
      }
    } else {
      // thread owns half-column: elements 8ri+4hb..+3 = ld[4ri..4ri+3]
      const int sw = ct0 & 7;
#pragma unroll
      for (int ri = 0; ri < 4; ++ri) {
        u32 hw[2], lw[2];
#pragma unroll
        for (int p = 0; p < 2; ++p) {        // pairs within the half-chunk
          int e = 4 * ri + 2 * p;            // ld index
          int n0e = n0 + 8 * ri + 4 * hb + 2 * p;
          float x0 = ld[e], x1 = ld[e + 1];
          x0 = (n0e     == gc0) ? 1.f : ((n0e     > gc0) ? x0 : 0.f);
          x1 = (n0e + 1 == gc0) ? 1.f : ((n0e + 1 > gc0) ? x1 : 0.f);
          pair_split(x0, x1, hw[p], lw[p]);
        }
        // chunk ri, word offset 2*hb (uint2 = half chunk)
        *(uint2*)&VT2[ct0][((((ri    ) ^ sw) << 2) + 2 * hb)] = *(uint2*)hw;
        *(uint2*)&VT2[ct0][((((ri + 4) ^ sw) << 2) + 2 * hb)] = *(uint2*)lw;
      }
    }
  };

  do_load(ns);
  for (int n0 = ns; n0 < ne; n0 += 32) {
    do_write(n0);
    __syncthreads();
    if (n0 + 32 < ne) do_load(n0 + 32);  // prefetch overlaps MFMA below

    bf16x8 Ah[4], Al[4];
#pragma unroll
    for (int mt = 0; mt < 4; ++mt) {
      int row = 64 * wr + 16 * mt + l15;
      read_frag2(&VT2[row][0], row, q, Ah[mt], Al[mt]);
    }
#pragma unroll
    for (int nt = 0; nt < 4; ++nt) {
      int brow = bbase + 64 * wc + 16 * nt + l15;
      bf16x8 bh, bl;
      read_frag2(&VT2[brow][0], brow, q, bh, bl);
#pragma unroll
      for (int mt = 0; mt < 4; ++mt)
        acc[mt][nt] = mm3(Ah[mt], Al[mt], bh, bl, acc[mt][nt]);
    }
    __syncthreads();
  }

  // C/D layout: col=lane&15, row=(lane>>4)*4+reg
  float* Sp = SP + (size_t)(chunk * 16 + b) * (R_ * R_);
#pragma unroll
  for (int mt = 0; mt < 4; ++mt)
#pragma unroll
    for (int nt = 0; nt < 4; ++nt) {
      int jj = j0 + 64 * wr + 16 * mt + 4 * q;
      int kk = k0 + 64 * wc + 16 * nt + l15;
#pragma unroll
      for (int r = 0; r < 4; ++r)
        Sp[(size_t)(jj + r) * R_ + kk] = acc[mt][nt][r];
    }
}

// ---------------------------------------------------------------------------
// reduce: sum 16 chunks into chunk 0, tile region only. grid (48, 16).
// ---------------------------------------------------------------------------
__global__ __launch_bounds__(256) void reduce_kernel(float* __restrict__ SP) {
  const int b = blockIdx.y;
  int j = blockIdx.x * 256 + threadIdx.x;
  int r, c4;
  if (j < 8192) { r = j >> 6; c4 = j & 63; }
  else { int jj = j - 8192; r = 128 + (jj >> 5); c4 = 32 + (jj & 31); }
  size_t idx = (size_t)b * 16384 + (size_t)r * 64 + c4;
  float4* sp = (float4*)SP;
  float4 a = sp[idx];
#pragma unroll
  for (int c = 1; c < 16; ++c) {
    float4 v = sp[idx + (size_t)c * 262144];
    a.x += v.x; a.y += v.y; a.z += v.z; a.w += v.w;
  }
  sp[idx] = a;
}

#define DPP_ADD(v, ctrl, rmask)                                              \
  v += __int_as_float(__builtin_amdgcn_update_dpp(                           \
      0, __float_as_int(v), ctrl, rmask, 0xf, true))

// ---------------------------------------------------------------------------
// K2: wave-per-column backward substitution over LDS-resident triangular S
// (R12 core). W emitted as RNE bf16 pairs.
// ---------------------------------------------------------------------------
__global__ __launch_bounds__(1024) void solve_kernel(const float* __restrict__ param,
                                                     const float* __restrict__ S,
                                                     u32* __restrict__ Whg) {
  extern __shared__ float tri[];
  const int t    = threadIdx.x;
  const int lane = t & 63;
  const int wave = t >> 6;
  const int b    = blockIdx.x >> 4;
  const int jg   = blockIdx.x & 15;
  const int k    = jg + 16 * wave;
  const float* __restrict__ Sb = S + (size_t)b * R_ * R_;
  const float* __restrict__ Pb = param + (size_t)b * N_ * R_;

  float4 x = *(const float4*)(Pb + (size_t)k * R_ + 4 * lane);
  {
    int c0 = 4 * lane;
    x.x = (c0     == k) ? 1.f : ((c0     < k) ? x.x : 0.f);
    x.y = (c0 + 1 == k) ? 1.f : ((c0 + 1 < k) ? x.y : 0.f);
    x.z = (c0 + 2 == k) ? 1.f : ((c0 + 2 < k) ? x.z : 0.f);
    x.w = (c0 + 3 == k) ? 1.f : ((c0 + 3 < k) ? x.w : 0.f);
  }

  const float4* S4 = (const float4*)Sb;
#pragma unroll
  for (int m = 0; m < 16; ++m) {
    int idx = t + 1024 * m;
    int r  = idx >> 6;
    int c4 = idx & 63;
    int g  = r >> 2;
    if (c4 >= g) {
      float4 v = S4[idx];
      int rowlen = 256 - 4 * g;
      int addr = 1024 * g - 8 * g * (g - 1) + (r & 3) * rowlen + 4 * (c4 - g);
      *(float4*)&tri[addr] = v;
    }
  }
  __syncthreads();

  float4 w = make_float4(0.f, 0.f, 0.f, 0.f);
  const int k4 = k >> 2;
  int rowlen = 256 - 4 * k4;
  int base   = 1024 * k4 - 8 * k4 * (k4 - 1);

  {
    const float* rb = tri + base + 4 * lane - 4 * k4;
    float4 rA0 = *(const float4*)(rb);
    float4 rA1 = *(const float4*)(rb + rowlen);
    float4 rA2 = *(const float4*)(rb + 2 * rowlen);
    float4 rA3 = *(const float4*)(rb + 3 * rowlen);

    for (int r4 = k4;; --r4) {
      const bool more = (r4 > 0);

      float s0 = fmaf(rA0.x, w.x, fmaf(rA0.y, w.y, fmaf(rA0.z, w.z, rA0.w * w.w)));
      float s1 = fmaf(rA1.x, w.x, fmaf(rA1.y, w.y, fmaf(rA1.z, w.z, rA1.w * w.w)));
      float s2 = fmaf(rA2.x, w.x, fmaf(rA2.y, w.y, fmaf(rA2.z, w.z, rA2.w * w.w)));
      float s3 = fmaf(rA3.x, w.x, fmaf(rA3.y, w.y, fmaf(rA3.z, w.z, rA3.w * w.w)));

      float4 rB0, rB1, rB2, rB3;
      int nrl = rowlen, nbs = base;
      if (more) {
        nrl = rowlen + 4;
        nbs = base - 4 * nrl;
        const float* rbn = tri + nbs + 4 * lane - 4 * (r4 - 1);
        rB0 = *(const float4*)(rbn);
        rB1 = *(const float4*)(rbn + nrl);
        rB2 = *(const float4*)(rbn + 2 * nrl);
        rB3 = *(const float4*)(rbn + 3 * nrl);
      }
      __builtin_amdgcn_sched_barrier(0);

      DPP_ADD(s0, 0x111, 0xf); DPP_ADD(s1, 0x111, 0xf);
      DPP_ADD(s2, 0x111, 0xf); DPP_ADD(s3, 0x111, 0xf);
      DPP_ADD(s0, 0x112, 0xf); DPP_ADD(s1, 0x112, 0xf);
      DPP_ADD(s2, 0x112, 0xf); DPP_ADD(s3, 0x112, 0xf);
      DPP_ADD(s0, 0x114, 0xf); DPP_ADD(s1, 0x114, 0xf);
      DPP_ADD(s2, 0x114, 0xf); DPP_ADD(s3, 0x114, 0xf);
      DPP_ADD(s0, 0x118, 0xf); DPP_ADD(s1, 0x118, 0xf);
      DPP_ADD(s2, 0x118, 0xf); DPP_ADD(s3, 0x118, 0xf);
      DPP_ADD(s0, 0x142, 0xa); DPP_ADD(s1, 0x142, 0xa);
      DPP_ADD(s2, 0x142, 0xa); DPP_ADD(s3, 0x142, 0xa);
      DPP_ADD(s0, 0x143, 0xc); DPP_ADD(s1, 0x143, 0xc);
      DPP_ADD(s2, 0x143, 0xc); DPP_ADD(s3, 0x143, 0xc);
      s0 = __int_as_float(__builtin_amdgcn_readlane(__float_as_int(s0), 63));
      s1 = __int_as_float(__builtin_amdgcn_readlane(__float_as_int(s1), 63));
      s2 = __int_as_float(__builtin_amdgcn_readlane(__float_as_int(s2), 63));
      s3 = __int_as_float(__builtin_amdgcn_readlane(__float_as_int(s3), 63));

      float w3 = 2.f * __builtin_amdgcn_rcpf(rA3.w) * (x.w - s3);
      float s2c = fmaf(rA2.w, w3, s2);
      float w2 = 2.f * __builtin_amdgcn_rcpf(rA2.z) * (x.z - s2c);
      float s1c = fmaf(rA1.z, w2, fmaf(rA1.w, w3, s1));
      float w1 = 2.f * __builtin_amdgcn_rcpf(rA1.y) * (x.y - s1c);
      float s0c = fmaf(rA0.y, w1, fmaf(rA0.z, w2, fmaf(rA0.w, w3, s0)));
      float w0 = 2.f * __builtin_amdgcn_rcpf(rA0.x) * (x.x - s0c);
      if (lane == r4) { w.w = w3; w.z = w2; w.y = w1; w.x = w0; }

      if (!more) break;
      rowlen = nrl; base = nbs;
      rA0 = rB0; rA1 = rB1; rA2 = rB2; rA3 = rB3;
    }
  }

  u32 p0 = rne16(w.x) | (rne16(w.y) << 16);
  u32 p1 = rne16(w.z) | (rne16(w.w) << 16);
  *(uint2*)(Whg + ((size_t)b * R_ + k) * 128 + 2 * lane) = make_uint2(p0, p1);
}

// ---------------------------------------------------------------------------
// K3: Q = E - V @ W via MFMA (R14 form, unchanged). grid (32, 2, 16).
// W bf16 (2 MFMAs/product), V fp32 DMA + split-on-read, 24 KB LDS.
// ---------------------------------------------------------------------------
__global__ __launch_bounds__(256) void final_kernel(const float* __restrict__ param,
                                                    const u32* __restrict__ Whg,
                                                    float* __restrict__ Q) {
  const int b  = blockIdx.z;
  const int n0 = blockIdx.x * 128;
  const int k0 = (blockIdx.y == 0) ? 128 : 0;   // long blocks first
  const float* __restrict__ Pb = param + (size_t)b * N_ * R_;
  const u32* __restrict__ Wb = Whg + (size_t)b * R_ * 128;
  float* __restrict__ Qb = Q + (size_t)b * N_ * R_;

  __shared__ struct {
    float VAf[128][32];
    u32   WBh[128][16];
  } sm;

  const int t = threadIdx.x;
  const int lane = t & 63, wv = t >> 6;
  const int wr = wv >> 1, wc = wv & 1;
  const int l15 = lane & 15, q = lane >> 4;
  const int rsub = lane >> 3;
  const int csub = lane & 7;
  const int wrow4 = lane >> 2;
  const int wch   = lane & 3;

  f32x4 acc[4][4];
#pragma unroll
  for (int i = 0; i < 4; ++i)
#pragma unroll
    for (int j = 0; j < 4; ++j) acc[i][j] = (f32x4){0.f, 0.f, 0.f, 0.f};

  auto issue = [&](int jb) {
#pragma unroll
    for (int c = 0; c < 4; ++c) {
      int rbase = 32 * c + 8 * wv;
      int row   = rbase + rsub;
      async_cp16(&sm.VAf[rbase][0],
                 &Pb[(size_t)(n0 + row) * R_ + jb + 4 * (csub ^ (row & 7))]);
    }
#pragma unroll
    for (int c = 0; c < 2; ++c) {
      int rbase = 16 * (wv + 4 * c);
      int row   = rbase + wrow4;
      async_cp16(&sm.WBh[rbase][0],
                 &Wb[(size_t)(k0 + row) * 128 + (jb >> 1) +
                     4 * (wch ^ ((row >> 1) & 3))]);
    }
  };

  const int jend = k0 + 128;
  issue(0);
  for (int jb = 0; jb < jend; jb += 32) {
    __syncthreads();

    if (n0 < 256 && n0 <= jb + 31) {
#pragma unroll
      for (int m = 0; m < 16; ++m) {
        int idx = t + 256 * m;
        int row = idx >> 5;
        int j   = idx & 31;
        int n   = n0 + row;
        int gj  = jb + j;
        if (n <= gj)
          sm.VAf[row][(((j >> 2) ^ (row & 7)) << 2) + (j & 3)] = (n == gj) ? 1.f : 0.f;
      }
      __syncthreads();
    }

    bf16x8 Ah[4], Al[4], Bh[4];
#pragma unroll
    for (int mt = 0; mt < 4; ++mt) {
      int row = 64 * wr + 16 * mt + l15;
      read_frag_f(&sm.VAf[row][0], row, 2 * q, Ah[mt], Al[mt]);
    }
#pragma unroll
    for (int nt = 0; nt < 4; ++nt) {
      int krow = 64 * wc + 16 * nt + l15;
      union { uint4 u; bf16x8 v; } X;
      X.u = *(const uint4*)(&sm.WBh[krow][(q ^ ((krow >> 1) & 3)) << 2]);
      Bh[nt] = X.v;
    }
    __syncthreads();

    if (jb + 32 < jend) issue(jb + 32);

#pragma unroll
    for (int nt = 0; nt < 4; ++nt)
#pragma unroll
      for (int mt = 0; mt < 4; ++mt) {
        acc[mt][nt] = __builtin_amdgcn_mfma_f32_16x16x32_bf16(
            Al[mt], Bh[nt], acc[mt][nt], 0, 0, 0);
        acc[mt][nt] = __builtin_amdgcn_mfma_f32_16x16x32_bf16(
            Ah[mt], Bh[nt], acc[mt][nt], 0, 0, 0);
      }
  }

  __syncthreads();

  float* Ep = (float*)&sm;
  const int erow = t >> 3;
  const int ec16 = (t & 7) * 16;
#pragma unroll
  for (int mt = 0; mt < 4; ++mt) {
    __syncthreads();
#pragma unroll
    for (int nt = 0; nt < 4; ++nt) {
      int kcol = k0 + 64 * wc + 16 * nt + l15;
#pragma unroll
      for (int r = 0; r < 4; ++r) {
        int nrow = n0 + 64 * wr + 16 * mt + 4 * q + r;
        int lrow = 16 * wr + 4 * q + r;
        Ep[lrow * 132 + 64 * wc + 16 * nt + l15] =
            ((nrow == kcol) ? 1.f : 0.f) - acc[mt][nt][r];
      }
    }
    __syncthreads();
    int grow = n0 + 64 * (erow >> 4) + 16 * mt + (erow & 15);
#pragma unroll
    for (int s = 0; s < 4; ++s) {
      float4 v = *(const float4*)&Ep[erow * 132 + ec16 + 4 * s];
      *(float4*)&Qb[(size_t)grow * R_ + k0 + ec16 + 4 * s] = v;
    }
  }
}

extern "C" void kernel_launch(void* const* d_in, const int* in_sizes, int n_in,
                              void* d_out, int out_size, void* d_ws, size_t ws_size,
                              hipStream_t stream) {
  const float* param = (const float*)d_in[0];
  float* Q  = (float*)d_out;
  // d_out during pipeline: SP = 16 chunks x 16 b x 256x256 fp32 (64 MB);
  // reduce folds chunks 1..15 into chunk 0 (= S) over the 3-tile region;
  // final overwrites everything with Q.
  float* SP = Q;
  float* S  = Q;
  u32*   Whg = (u32*)d_ws;  // 2 MB: RNE bf16 pairs of W^T

  gram_kernel<<<dim3(3, 16, B_), 256, 0, stream>>>(param, SP);
  reduce_kernel<<<dim3(48, 16), 256, 0, stream>>>(SP);
  solve_kernel<<<dim3(256), 1024, 133120, stream>>>(param, S, Whg);
  final_kernel<<<dim3(32, 2, B_), 256, 0, stream>>>(param, Whg, Q);
}